// Round 2
// baseline (303.072 us; speedup 1.0000x reference)
//
#include <hip/hip_runtime.h>
#include <hip/hip_bf16.h>

#define N_NODES 20000
#define DIM 128
#define N_EDGES 500000
#define BATCH 16384
#define EPS 1e-6f

typedef _Float16 half8 __attribute__((ext_vector_type(8)));
typedef _Float16 half4_t __attribute__((ext_vector_type(4)));
typedef float f32x4 __attribute__((ext_vector_type(4)));

// ---- workspace layout (bytes) ----
#define NB_GEMM (256 * 256)          // 65536 gemm partials (one per block incl. skipped)
#define NB_LINK 2048                 // link partials
#define OFF_PGEMM 0
#define OFF_PLINK (NB_GEMM * 4)                       // 262144
#define OFF_PSH   (OFF_PLINK + NB_LINK * 4)           // 270336
#define OFF_PPH   (OFF_PSH + BATCH * DIM * 2)         // + 4 MiB
#define OFF_N2S   (OFF_PPH + BATCH * DIM * 2)         // + 4 MiB
#define OFF_N2P   (OFF_N2S + BATCH * 4)
#define OFF_BPS   (OFF_N2P + BATCH * 4)
#define OFF_BP    (OFF_BPS + BATCH * 4)
// total ~8.93 MB

// Gather rows of `pts` by idx, convert to fp16, store row norms (fp32) and gathered beta.
// 256 threads = 8 rows/block, 32 lanes per row (float4 each => 128 floats).
__global__ __launch_bounds__(256) void gather_kernel(
    const float* __restrict__ pts, const float* __restrict__ beta,
    const int* __restrict__ idx,
    _Float16* __restrict__ dst, float* __restrict__ n2, float* __restrict__ bdst)
{
    int g = threadIdx.x & 31;
    int row = blockIdx.x * 8 + (threadIdx.x >> 5);
    int id = idx[row];
    float4 v = ((const float4*)(pts + (size_t)id * DIM))[g];
    half4_t o;
    o[0] = (_Float16)v.x; o[1] = (_Float16)v.y; o[2] = (_Float16)v.z; o[3] = (_Float16)v.w;
    *(half4_t*)(dst + (size_t)row * DIM + g * 4) = o;
    float nrm = v.x * v.x + v.y * v.y + v.z * v.z + v.w * v.w;
    #pragma unroll
    for (int m = 16; m >= 1; m >>= 1) nrm += __shfl_xor(nrm, m, 32);
    if (g == 0) {
        n2[row] = nrm;
        bdst[row] = beta[id];
    }
}

// Link term: 32 lanes per edge; block partial sums (no atomics).
__global__ __launch_bounds__(256) void link_kernel(
    const int* __restrict__ edges,
    const float* __restrict__ beta_p, const float* __restrict__ beta_ps,
    const float* __restrict__ p, const float* __restrict__ p_star,
    float* __restrict__ partial)
{
    int g = threadIdx.x & 31;
    float tacc = 0.f;
    for (int e = blockIdx.x * 8 + (threadIdx.x >> 5); e < N_EDGES; e += gridDim.x * 8) {
        int e0 = edges[e];
        int e1 = edges[N_EDGES + e];
        float4 a = ((const float4*)(p + (size_t)e0 * DIM))[g];
        float4 b = ((const float4*)(p_star + (size_t)e1 * DIM))[g];
        float dx = a.x - b.x + EPS;
        float dy = a.y - b.y + EPS;
        float dz = a.z - b.z + EPS;
        float dw = a.w - b.w + EPS;
        float s = dx * dx + dy * dy + dz * dz + dw * dw;
        #pragma unroll
        for (int m = 16; m >= 1; m >>= 1) s += __shfl_xor(s, m, 32);
        if (g == 0) {
            float bsum = beta_ps[e0] + beta_p[e1];
            tacc += bsum - sqrtf(s);
        }
    }
    // block reduce 256 -> 1
    #pragma unroll
    for (int m = 32; m >= 1; m >>= 1) tacc += __shfl_xor(tacc, m, 64);
    __shared__ float sm[4];
    int w = threadIdx.x >> 6;
    if ((threadIdx.x & 63) == 0) sm[w] = tacc;
    __syncthreads();
    if (threadIdx.x == 0) partial[blockIdx.x] = sm[0] + sm[1] + sm[2] + sm[3];
}

// Non-link: 64x64 tile per block, 4 waves, each wave a 32x32 subtile (2x2 of 16x16 MFMA).
// A = ps (M=Ns rows), B = pp (N=Np rows), K=128. acc = ps_i . pp_j
__global__ __launch_bounds__(256) void nonlink_kernel(
    const _Float16* __restrict__ Ag, const _Float16* __restrict__ Bg,
    const float* __restrict__ n2A, const float* __restrict__ n2B,
    const float* __restrict__ bA, const float* __restrict__ bB,
    float* __restrict__ partial)
{
    const int i0 = blockIdx.y * 64;
    const int j0 = blockIdx.x * 64;
    const int bid = blockIdx.y * gridDim.x + blockIdx.x;
    if (j0 + 63 <= i0) {  // no element with j > i in this tile
        if (threadIdx.x == 0) partial[bid] = 0.f;
        return;
    }

    // +8 element pad => 272B row stride => 2-way LDS bank aliasing (free)
    __shared__ __align__(16) _Float16 As[64][136];
    __shared__ __align__(16) _Float16 Bs[64][136];

    const int tid = threadIdx.x;
    // stage both tiles: each row is 128 halves = 16 chunks of 16B; 64 rows
    // => 1024 chunks per tile, 4 per thread per tile.
    #pragma unroll
    for (int c = tid; c < 1024; c += 256) {
        int row = c >> 4;
        int col = (c & 15) * 8;  // elements
        *(uint4*)&As[row][col] = *(const uint4*)(Ag + (size_t)(i0 + row) * DIM + col);
        *(uint4*)&Bs[row][col] = *(const uint4*)(Bg + (size_t)(j0 + row) * DIM + col);
    }
    __syncthreads();

    const int lane = tid & 63;
    const int w = tid >> 6;
    const int wm = w & 1;        // wave's M half
    const int wn = w >> 1;       // wave's N half
    const int quad = lane >> 4;  // 0..3
    const int lr = lane & 15;

    f32x4 acc[2][2] = {};
    #pragma unroll
    for (int ks = 0; ks < 4; ++ks) {
        int koff = ks * 32 + quad * 8;
        half8 a0 = *(const half8*)&As[wm * 32 + lr][koff];
        half8 a1 = *(const half8*)&As[wm * 32 + 16 + lr][koff];
        half8 b0 = *(const half8*)&Bs[wn * 32 + lr][koff];
        half8 b1 = *(const half8*)&Bs[wn * 32 + 16 + lr][koff];
        acc[0][0] = __builtin_amdgcn_mfma_f32_16x16x32_f16(a0, b0, acc[0][0], 0, 0, 0);
        acc[0][1] = __builtin_amdgcn_mfma_f32_16x16x32_f16(a0, b1, acc[0][1], 0, 0, 0);
        acc[1][0] = __builtin_amdgcn_mfma_f32_16x16x32_f16(a1, b0, acc[1][0], 0, 0, 0);
        acc[1][1] = __builtin_amdgcn_mfma_f32_16x16x32_f16(a1, b1, acc[1][1], 0, 0, 0);
    }

    // epilogue: C/D layout col=lane&15, row=quad*4+reg  [verified m89/m91]
    float lsum = 0.f;
    #pragma unroll
    for (int mi = 0; mi < 2; ++mi) {
        int ibase = i0 + wm * 32 + mi * 16 + quad * 4;
        float4 n2i = *(const float4*)&n2A[ibase];  // 16B aligned (ibase % 4 == 0)
        float4 bi = *(const float4*)&bA[ibase];
        #pragma unroll
        for (int ni = 0; ni < 2; ++ni) {
            int j = j0 + wn * 32 + ni * 16 + lr;
            float n2j = n2B[j];
            float bj = bB[j];
            f32x4 d = acc[mi][ni];
            #pragma unroll
            for (int r = 0; r < 4; ++r) {
                int i = ibase + r;
                float sq = ((const float*)&n2i)[r] + n2j - 2.f * d[r];
                float dist = sqrtf(fmaxf(sq, 0.f));
                float ex = __expf(((const float*)&bi)[r] + bj - dist);
                if (j > i) lsum += ex;
            }
        }
    }

    // block reduce
    #pragma unroll
    for (int m = 32; m >= 1; m >>= 1) lsum += __shfl_xor(lsum, m, 64);
    __shared__ float sm[4];
    if ((lane) == 0) sm[w] = lsum;
    __syncthreads();
    if (tid == 0) partial[bid] = sm[0] + sm[1] + sm[2] + sm[3];
}

__global__ __launch_bounds__(1024) void final_kernel(
    const float* __restrict__ pg, const float* __restrict__ pl, float* __restrict__ out)
{
    float s = 0.f;
    for (int k = threadIdx.x; k < NB_GEMM; k += 1024) s += pg[k];
    for (int k = threadIdx.x; k < NB_LINK; k += 1024) s -= pl[k];
    #pragma unroll
    for (int m = 32; m >= 1; m >>= 1) s += __shfl_xor(s, m, 64);
    __shared__ float sm[16];
    int w = threadIdx.x >> 6;
    if ((threadIdx.x & 63) == 0) sm[w] = s;
    __syncthreads();
    if (threadIdx.x == 0) {
        float t = 0.f;
        #pragma unroll
        for (int i = 0; i < 16; ++i) t += sm[i];
        out[0] = t;  // non_link - link_term == -(link - non_link)
    }
}

extern "C" void kernel_launch(void* const* d_in, const int* in_sizes, int n_in,
                              void* d_out, int out_size, void* d_ws, size_t ws_size,
                              hipStream_t stream) {
    const int* edges = (const int*)d_in[0];
    const int* nodes_p_star = (const int*)d_in[1];
    const int* nodes_p = (const int*)d_in[2];
    const float* beta_p = (const float*)d_in[3];
    const float* beta_p_star = (const float*)d_in[4];
    const float* p = (const float*)d_in[5];
    const float* p_star = (const float*)d_in[6];

    char* ws = (char*)d_ws;
    float* pgemm = (float*)(ws + OFF_PGEMM);
    float* plink = (float*)(ws + OFF_PLINK);
    _Float16* psh = (_Float16*)(ws + OFF_PSH);   // gathered p_star rows (A / Ns)
    _Float16* pph = (_Float16*)(ws + OFF_PPH);   // gathered p rows (B / Np)
    float* n2s = (float*)(ws + OFF_N2S);
    float* n2p = (float*)(ws + OFF_N2P);
    float* bps = (float*)(ws + OFF_BPS);
    float* bp = (float*)(ws + OFF_BP);

    // gather+convert: A <- p_star[nodes_p_star], B <- p[nodes_p]
    gather_kernel<<<BATCH / 8, 256, 0, stream>>>(p_star, beta_p_star, nodes_p_star, psh, n2s, bps);
    gather_kernel<<<BATCH / 8, 256, 0, stream>>>(p, beta_p, nodes_p, pph, n2p, bp);

    link_kernel<<<NB_LINK, 256, 0, stream>>>(edges, beta_p, beta_p_star, p, p_star, plink);

    nonlink_kernel<<<dim3(256, 256), 256, 0, stream>>>(psh, pph, n2s, n2p, bps, bp, pgemm);

    final_kernel<<<1, 1024, 0, stream>>>(pgemm, plink, (float*)d_out);
}

// Round 3
// 252.440 us; speedup vs baseline: 1.2006x; 1.2006x over previous
//
#include <hip/hip_runtime.h>
#include <hip/hip_bf16.h>

#define N_NODES 20000
#define DIM 128
#define N_EDGES 500000
#define BATCH 16384
#define EPS 1e-6f

typedef _Float16 half8 __attribute__((ext_vector_type(8)));
typedef _Float16 half4_t __attribute__((ext_vector_type(4)));
typedef float f32x4 __attribute__((ext_vector_type(4)));

__device__ __forceinline__ float fast_sqrtf(float x) {
#if __has_builtin(__builtin_amdgcn_sqrtf)
    return __builtin_amdgcn_sqrtf(x);   // bare v_sqrt_f32, ~1 ulp
#else
    return sqrtf(x);
#endif
}

// ---- workspace layout (bytes) ----
#define NB_GEMM 32896                 // 257*128 triangular tiles
#define NB_LINK 15625                 // link blocks (32 edges each)
#define NB_FIN  128
#define OFF_PGEMM 0
#define OFF_PLINK 131584              // 32896*4
#define OFF_FPART 194112              // 131584+62500 -> 64B aligned
#define OFF_PSH   194624
#define OFF_PPH   4388928             // + 16384*128*2
#define OFF_N2S   8583232
#define OFF_N2P   8648768
#define OFF_BPS   8714304
#define OFF_BP    8779840
// total 8845376 B (~8.44 MB), less than round-2's 8.92 MB (which fit)

// Gather rows of `pts` by idx, convert to fp16, store row norms (fp32) and gathered beta.
__global__ __launch_bounds__(256) void gather_kernel(
    const float* __restrict__ pts, const float* __restrict__ beta,
    const int* __restrict__ idx,
    _Float16* __restrict__ dst, float* __restrict__ n2, float* __restrict__ bdst)
{
    int g = threadIdx.x & 31;
    int row = blockIdx.x * 8 + (threadIdx.x >> 5);
    int id = idx[row];
    float4 v = ((const float4*)(pts + (size_t)id * DIM))[g];
    half4_t o;
    o[0] = (_Float16)v.x; o[1] = (_Float16)v.y; o[2] = (_Float16)v.z; o[3] = (_Float16)v.w;
    *(half4_t*)(dst + (size_t)row * DIM + g * 4) = o;
    float nrm = v.x * v.x + v.y * v.y + v.z * v.z + v.w * v.w;
    #pragma unroll
    for (int m = 16; m >= 1; m >>= 1) nrm += __shfl_xor(nrm, m, 32);
    if (g == 0) {
        n2[row] = nrm;
        bdst[row] = beta[id];
    }
}

// Link term: 32 lanes per edge, 4 edges per 32-group, 15625 blocks (no grid-stride).
__global__ __launch_bounds__(256) void link_kernel(
    const int* __restrict__ edges,
    const float* __restrict__ beta_p, const float* __restrict__ beta_ps,
    const float* __restrict__ p, const float* __restrict__ p_star,
    float* __restrict__ partial)
{
    int g = threadIdx.x & 31;
    int base = blockIdx.x * 32 + (threadIdx.x >> 5) * 4;
    float tacc = 0.f;
    #pragma unroll
    for (int t = 0; t < 4; ++t) {
        int e = base + t;
        int e0 = edges[e];
        int e1 = edges[N_EDGES + e];
        float4 a = ((const float4*)(p + (size_t)e0 * DIM))[g];
        float4 b = ((const float4*)(p_star + (size_t)e1 * DIM))[g];
        float dx = a.x - b.x + EPS;
        float dy = a.y - b.y + EPS;
        float dz = a.z - b.z + EPS;
        float dw = a.w - b.w + EPS;
        float s = dx * dx + dy * dy + dz * dz + dw * dw;
        #pragma unroll
        for (int m = 16; m >= 1; m >>= 1) s += __shfl_xor(s, m, 32);
        if (g == 0) {
            float bsum = beta_ps[e0] + beta_p[e1];
            tacc += bsum - fast_sqrtf(s);
        }
    }
    #pragma unroll
    for (int m = 32; m >= 1; m >>= 1) tacc += __shfl_xor(tacc, m, 64);
    __shared__ float sm[4];
    int w = threadIdx.x >> 6;
    if ((threadIdx.x & 63) == 0) sm[w] = tacc;
    __syncthreads();
    if (threadIdx.x == 0) partial[blockIdx.x] = sm[0] + sm[1] + sm[2] + sm[3];
}

// Non-link: triangular grid (257 x 128) -> exactly the 32896 tiles with tj >= ti.
// 64x64 tile per block, 4 waves, each wave a 32x32 subtile (2x2 of 16x16 MFMA).
__global__ __launch_bounds__(256) void nonlink_kernel(
    const _Float16* __restrict__ Ag, const _Float16* __restrict__ Bg,
    const float* __restrict__ n2A, const float* __restrict__ n2B,
    const float* __restrict__ bA, const float* __restrict__ bB,
    float* __restrict__ partial)
{
    // wrapped-triangle mapping: rows {by} and {255-by} share a y-slot
    const int bx = blockIdx.x, by = blockIdx.y;
    int ti, tj;
    if (bx >= by && bx < 256) { ti = by; tj = bx; }
    else { int u = (bx >= 256) ? by : bx; ti = 255 - by; tj = 255 - u; }
    const int i0 = ti * 64;
    const int j0 = tj * 64;
    const int bid = by * 257 + bx;
    const bool diag = (ti == tj);

    __shared__ __align__(16) _Float16 As[64][136];  // +8 pad: 2-way aliasing only (free)
    __shared__ __align__(16) _Float16 Bs[64][136];

    const int tid = threadIdx.x;
    #pragma unroll
    for (int c = tid; c < 1024; c += 256) {
        int row = c >> 4;
        int col = (c & 15) * 8;
        *(uint4*)&As[row][col] = *(const uint4*)(Ag + (size_t)(i0 + row) * DIM + col);
        *(uint4*)&Bs[row][col] = *(const uint4*)(Bg + (size_t)(j0 + row) * DIM + col);
    }
    __syncthreads();

    const int lane = tid & 63;
    const int w = tid >> 6;
    const int wm = w & 1;
    const int wn = w >> 1;
    const int quad = lane >> 4;
    const int lr = lane & 15;

    f32x4 acc[2][2] = {};
    #pragma unroll
    for (int ks = 0; ks < 4; ++ks) {
        int koff = ks * 32 + quad * 8;
        half8 a0 = *(const half8*)&As[wm * 32 + lr][koff];
        half8 a1 = *(const half8*)&As[wm * 32 + 16 + lr][koff];
        half8 b0 = *(const half8*)&Bs[wn * 32 + lr][koff];
        half8 b1 = *(const half8*)&Bs[wn * 32 + 16 + lr][koff];
        acc[0][0] = __builtin_amdgcn_mfma_f32_16x16x32_f16(a0, b0, acc[0][0], 0, 0, 0);
        acc[0][1] = __builtin_amdgcn_mfma_f32_16x16x32_f16(a0, b1, acc[0][1], 0, 0, 0);
        acc[1][0] = __builtin_amdgcn_mfma_f32_16x16x32_f16(a1, b0, acc[1][0], 0, 0, 0);
        acc[1][1] = __builtin_amdgcn_mfma_f32_16x16x32_f16(a1, b1, acc[1][1], 0, 0, 0);
    }

    // epilogue: C/D layout col=lane&15, row=quad*4+reg
    float lsum = 0.f;
    if (!diag) {
        // interior tile: every (i,j) has j > i -- no mask
        #pragma unroll
        for (int mi = 0; mi < 2; ++mi) {
            int rbase = wm * 32 + mi * 16 + quad * 4;
            float4 n2i = *(const float4*)&n2A[i0 + rbase];
            float4 bi = *(const float4*)&bA[i0 + rbase];
            #pragma unroll
            for (int ni = 0; ni < 2; ++ni) {
                int jc = wn * 32 + ni * 16 + lr;
                float n2j = n2B[j0 + jc];
                float bj = bB[j0 + jc];
                f32x4 d = acc[mi][ni];
                #pragma unroll
                for (int r = 0; r < 4; ++r) {
                    float sq = fmaxf(((const float*)&n2i)[r] + n2j - 2.f * d[r], 0.f);
                    float dist = fast_sqrtf(sq);
                    lsum += __expf(((const float*)&bi)[r] + bj - dist);
                }
            }
        }
    } else {
        #pragma unroll
        for (int mi = 0; mi < 2; ++mi) {
            int rbase = wm * 32 + mi * 16 + quad * 4;
            float4 n2i = *(const float4*)&n2A[i0 + rbase];
            float4 bi = *(const float4*)&bA[i0 + rbase];
            #pragma unroll
            for (int ni = 0; ni < 2; ++ni) {
                int jc = wn * 32 + ni * 16 + lr;
                float n2j = n2B[j0 + jc];
                float bj = bB[j0 + jc];
                f32x4 d = acc[mi][ni];
                #pragma unroll
                for (int r = 0; r < 4; ++r) {
                    float sq = fmaxf(((const float*)&n2i)[r] + n2j - 2.f * d[r], 0.f);
                    float dist = fast_sqrtf(sq);
                    float ex = __expf(((const float*)&bi)[r] + bj - dist);
                    if (jc > rbase + r) lsum += ex;   // i0 == j0 on diagonal tiles
                }
            }
        }
    }

    #pragma unroll
    for (int m = 32; m >= 1; m >>= 1) lsum += __shfl_xor(lsum, m, 64);
    __shared__ float sm[4];
    if (lane == 0) sm[w] = lsum;
    __syncthreads();
    if (tid == 0) partial[bid] = sm[0] + sm[1] + sm[2] + sm[3];
}

// stage 1: grid-stride partial sums (gemm positive, link negative) -> 128 values
__global__ __launch_bounds__(256) void reduce1_kernel(
    const float* __restrict__ pg, const float* __restrict__ pl, float* __restrict__ fpart)
{
    float s = 0.f;
    for (int k = blockIdx.x * 256 + threadIdx.x; k < NB_GEMM; k += 128 * 256) s += pg[k];
    for (int k = blockIdx.x * 256 + threadIdx.x; k < NB_LINK; k += 128 * 256) s -= pl[k];
    #pragma unroll
    for (int m = 32; m >= 1; m >>= 1) s += __shfl_xor(s, m, 64);
    __shared__ float sm[4];
    int w = threadIdx.x >> 6;
    if ((threadIdx.x & 63) == 0) sm[w] = s;
    __syncthreads();
    if (threadIdx.x == 0) fpart[blockIdx.x] = sm[0] + sm[1] + sm[2] + sm[3];
}

// stage 2: 128 -> 1
__global__ __launch_bounds__(128) void reduce2_kernel(
    const float* __restrict__ fpart, float* __restrict__ out)
{
    float s = fpart[threadIdx.x];
    #pragma unroll
    for (int m = 32; m >= 1; m >>= 1) s += __shfl_xor(s, m, 64);
    __shared__ float sm[2];
    if ((threadIdx.x & 63) == 0) sm[threadIdx.x >> 6] = s;
    __syncthreads();
    if (threadIdx.x == 0) out[0] = sm[0] + sm[1];
}

extern "C" void kernel_launch(void* const* d_in, const int* in_sizes, int n_in,
                              void* d_out, int out_size, void* d_ws, size_t ws_size,
                              hipStream_t stream) {
    const int* edges = (const int*)d_in[0];
    const int* nodes_p_star = (const int*)d_in[1];
    const int* nodes_p = (const int*)d_in[2];
    const float* beta_p = (const float*)d_in[3];
    const float* beta_p_star = (const float*)d_in[4];
    const float* p = (const float*)d_in[5];
    const float* p_star = (const float*)d_in[6];

    char* ws = (char*)d_ws;
    float* pgemm = (float*)(ws + OFF_PGEMM);
    float* plink = (float*)(ws + OFF_PLINK);
    float* fpart = (float*)(ws + OFF_FPART);
    _Float16* psh = (_Float16*)(ws + OFF_PSH);   // gathered p_star rows (A / Ns)
    _Float16* pph = (_Float16*)(ws + OFF_PPH);   // gathered p rows (B / Np)
    float* n2s = (float*)(ws + OFF_N2S);
    float* n2p = (float*)(ws + OFF_N2P);
    float* bps = (float*)(ws + OFF_BPS);
    float* bp = (float*)(ws + OFF_BP);

    gather_kernel<<<BATCH / 8, 256, 0, stream>>>(p_star, beta_p_star, nodes_p_star, psh, n2s, bps);
    gather_kernel<<<BATCH / 8, 256, 0, stream>>>(p, beta_p, nodes_p, pph, n2p, bp);

    link_kernel<<<NB_LINK, 256, 0, stream>>>(edges, beta_p, beta_p_star, p, p_star, plink);

    nonlink_kernel<<<dim3(257, 128), 256, 0, stream>>>(psh, pph, n2s, n2p, bps, bp, pgemm);

    reduce1_kernel<<<NB_FIN, 256, 0, stream>>>(pgemm, plink, fpart);
    reduce2_kernel<<<1, 128, 0, stream>>>(fpart, (float*)d_out);
}

// Round 4
// 211.922 us; speedup vs baseline: 1.4301x; 1.1912x over previous
//
#include <hip/hip_runtime.h>
#include <hip/hip_bf16.h>

#define N_NODES 20000
#define DIM 128
#define N_EDGES 500000
#define BATCH 16384
#define EPS 1e-6f

typedef _Float16 half8 __attribute__((ext_vector_type(8)));
typedef _Float16 half4_t __attribute__((ext_vector_type(4)));
typedef float f32x4 __attribute__((ext_vector_type(4)));

__device__ __forceinline__ float fast_sqrtf(float x) {
#if __has_builtin(__builtin_amdgcn_sqrtf)
    return __builtin_amdgcn_sqrtf(x);   // bare v_sqrt_f32, ~1 ulp
#else
    return sqrtf(x);
#endif
}

// ---- sizes ----
#define NB_GEMM 8256                  // 129*64 triangular 128-tiles
#define NB_LINK16 31250               // fp16 link: 16 edges/block
#define NB_LINK32 15625               // fp32 fallback link: 32 edges/block
#define NB_FIN  128

// ---- workspace layout (bytes, 64B aligned) ----
#define OFF_PGEMM 0
#define OFF_PLINK 33024
#define OFF_FPART 158080
#define OFF_PSH   158592
#define OFF_PPH   4352896
#define OFF_N2S   8547200
#define OFF_N2P   8612736
#define OFF_BPS   8678272
#define OFF_BP    8743808
#define OFF_BASE_END 8809344          // fp32-fallback footprint
#define OFF_P16   8809344             // fp16 copy of p       (20000*128*2)
#define OFF_PS16  13929344            // fp16 copy of p_star
#define OFF_END   19049344            // fp16-link footprint (~18.2 MB)

// Gather rows of `pts` by batch idx, convert to fp16, store fp32 row norms + beta.
__global__ __launch_bounds__(256) void gather_kernel(
    const float* __restrict__ pts, const float* __restrict__ beta,
    const int* __restrict__ idx,
    _Float16* __restrict__ dst, float* __restrict__ n2, float* __restrict__ bdst)
{
    int g = threadIdx.x & 31;
    int row = blockIdx.x * 8 + (threadIdx.x >> 5);
    int id = idx[row];
    float4 v = ((const float4*)(pts + (size_t)id * DIM))[g];
    half4_t o;
    o[0] = (_Float16)v.x; o[1] = (_Float16)v.y; o[2] = (_Float16)v.z; o[3] = (_Float16)v.w;
    *(half4_t*)(dst + (size_t)row * DIM + g * 4) = o;
    float nrm = v.x * v.x + v.y * v.y + v.z * v.z + v.w * v.w;
    #pragma unroll
    for (int m = 16; m >= 1; m >>= 1) nrm += __shfl_xor(nrm, m, 32);
    if (g == 0) {
        n2[row] = nrm;
        bdst[row] = beta[id];
    }
}

// Convert a full fp32 table (20000 x 128) to fp16. 8 rows/block -> 2500 blocks.
__global__ __launch_bounds__(256) void convert_kernel(
    const float* __restrict__ src, _Float16* __restrict__ dst)
{
    int g = threadIdx.x & 31;
    int row = blockIdx.x * 8 + (threadIdx.x >> 5);
    float4 v = ((const float4*)(src + (size_t)row * DIM))[g];
    half4_t o;
    o[0] = (_Float16)v.x; o[1] = (_Float16)v.y; o[2] = (_Float16)v.z; o[3] = (_Float16)v.w;
    *(half4_t*)(dst + (size_t)row * DIM + g * 4) = o;
}

// Link term, fp16 tables: 16 lanes/edge (half8 = 16B per lane), 16 edges/block.
__global__ __launch_bounds__(256) void link16_kernel(
    const int* __restrict__ edges,
    const float* __restrict__ beta_p, const float* __restrict__ beta_ps,
    const _Float16* __restrict__ p16, const _Float16* __restrict__ ps16,
    float* __restrict__ partial)
{
    int g = threadIdx.x & 15;
    int grp = threadIdx.x >> 4;           // 0..15
    int e = blockIdx.x * 16 + grp;
    int e0 = edges[e];
    int e1 = edges[N_EDGES + e];
    half8 a = *(const half8*)(p16 + (size_t)e0 * DIM + g * 8);
    half8 b = *(const half8*)(ps16 + (size_t)e1 * DIM + g * 8);
    float s = 0.f;
    #pragma unroll
    for (int k = 0; k < 8; ++k) {
        float d = (float)a[k] - (float)b[k] + EPS;
        s = fmaf(d, d, s);
    }
    #pragma unroll
    for (int m = 8; m >= 1; m >>= 1) s += __shfl_xor(s, m, 16);
    __shared__ float sm[16];
    if (g == 0) {
        float bsum = beta_ps[e0] + beta_p[e1];
        sm[grp] = bsum - fast_sqrtf(s);
    }
    __syncthreads();
    if (threadIdx.x == 0) {
        float t = 0.f;
        #pragma unroll
        for (int i = 0; i < 16; ++i) t += sm[i];
        partial[blockIdx.x] = t;
    }
}

// Link term, fp32 fallback (if ws too small for fp16 tables): 32 lanes/edge.
__global__ __launch_bounds__(256) void link32_kernel(
    const int* __restrict__ edges,
    const float* __restrict__ beta_p, const float* __restrict__ beta_ps,
    const float* __restrict__ p, const float* __restrict__ p_star,
    float* __restrict__ partial)
{
    int g = threadIdx.x & 31;
    int base = blockIdx.x * 32 + (threadIdx.x >> 5) * 4;
    float tacc = 0.f;
    #pragma unroll
    for (int t = 0; t < 4; ++t) {
        int e = base + t;
        int e0 = edges[e];
        int e1 = edges[N_EDGES + e];
        float4 a = ((const float4*)(p + (size_t)e0 * DIM))[g];
        float4 b = ((const float4*)(p_star + (size_t)e1 * DIM))[g];
        float dx = a.x - b.x + EPS;
        float dy = a.y - b.y + EPS;
        float dz = a.z - b.z + EPS;
        float dw = a.w - b.w + EPS;
        float s = dx * dx + dy * dy + dz * dz + dw * dw;
        #pragma unroll
        for (int m = 16; m >= 1; m >>= 1) s += __shfl_xor(s, m, 32);
        if (g == 0) tacc += (beta_ps[e0] + beta_p[e1]) - fast_sqrtf(s);
    }
    #pragma unroll
    for (int m = 32; m >= 1; m >>= 1) tacc += __shfl_xor(tacc, m, 64);
    __shared__ float sm[4];
    int w = threadIdx.x >> 6;
    if ((threadIdx.x & 63) == 0) sm[w] = tacc;
    __syncthreads();
    if (threadIdx.x == 0) partial[blockIdx.x] = sm[0] + sm[1] + sm[2] + sm[3];
}

// Non-link: triangular grid (129 x 64) of 128x128 tiles. 4 waves; each wave a
// 64x64 subtile = 4x4 frags of 16x16x32 MFMA.
__global__ __launch_bounds__(256) void nonlink_kernel(
    const _Float16* __restrict__ Ag, const _Float16* __restrict__ Bg,
    const float* __restrict__ n2A, const float* __restrict__ n2B,
    const float* __restrict__ bA, const float* __restrict__ bB,
    float* __restrict__ partial)
{
    // wrapped-triangle mapping over 128 tile-rows
    const int bx = blockIdx.x, by = blockIdx.y;
    int ti, tj;
    if (bx >= by && bx < 128) { ti = by; tj = bx; }
    else { int u = (bx >= 128) ? by : bx; ti = 127 - by; tj = 127 - u; }
    const int i0 = ti * 128;
    const int j0 = tj * 128;
    const int bid = by * 129 + bx;
    const bool diag = (ti == tj);

    __shared__ __align__(16) _Float16 As[128][136];  // +8 pad (272B stride)
    __shared__ __align__(16) _Float16 Bs[128][136];

    const int tid = threadIdx.x;
    // 128 rows x 16 chunks(16B) per array = 2048 chunks, 8 per thread per array
    #pragma unroll
    for (int c = tid; c < 2048; c += 256) {
        int row = c >> 4;
        int col = (c & 15) * 8;
        *(uint4*)&As[row][col] = *(const uint4*)(Ag + (size_t)(i0 + row) * DIM + col);
        *(uint4*)&Bs[row][col] = *(const uint4*)(Bg + (size_t)(j0 + row) * DIM + col);
    }
    __syncthreads();

    const int lane = tid & 63;
    const int w = tid >> 6;
    const int wm = w & 1;
    const int wn = w >> 1;
    const int quad = lane >> 4;
    const int lr = lane & 15;

    float lsum = 0.f;
    const bool dead = diag && (wm > wn);     // fully below diagonal
    if (!dead) {
        f32x4 acc[4][4] = {};
        #pragma unroll
        for (int ks = 0; ks < 4; ++ks) {
            int koff = ks * 32 + quad * 8;
            half8 af[4], bf[4];
            #pragma unroll
            for (int t = 0; t < 4; ++t) {
                af[t] = *(const half8*)&As[wm * 64 + t * 16 + lr][koff];
                bf[t] = *(const half8*)&Bs[wn * 64 + t * 16 + lr][koff];
            }
            #pragma unroll
            for (int mi = 0; mi < 4; ++mi)
                #pragma unroll
                for (int ni = 0; ni < 4; ++ni)
                    acc[mi][ni] = __builtin_amdgcn_mfma_f32_16x16x32_f16(af[mi], bf[ni], acc[mi][ni], 0, 0, 0);
        }

        // epilogue: C/D layout col=lane&15, row=quad*4+reg
        const bool masked = diag && (wm == wn);
        #pragma unroll
        for (int mi = 0; mi < 4; ++mi) {
            int rbase = wm * 64 + mi * 16 + quad * 4;   // tile-local row base
            float4 n2i = *(const float4*)&n2A[i0 + rbase];
            float4 bi = *(const float4*)&bA[i0 + rbase];
            #pragma unroll
            for (int ni = 0; ni < 4; ++ni) {
                int jc = wn * 64 + ni * 16 + lr;        // tile-local col
                float n2j = n2B[j0 + jc];
                float bj = bB[j0 + jc];
                f32x4 d = acc[mi][ni];
                #pragma unroll
                for (int r = 0; r < 4; ++r) {
                    float sq = fmaxf(((const float*)&n2i)[r] + n2j - 2.f * d[r], 0.f);
                    float dist = fast_sqrtf(sq);
                    float ex = __expf(((const float*)&bi)[r] + bj - dist);
                    if (!masked || jc > rbase + r) lsum += ex;
                }
            }
        }
    }

    #pragma unroll
    for (int m = 32; m >= 1; m >>= 1) lsum += __shfl_xor(lsum, m, 64);
    __shared__ float smr[4];
    if (lane == 0) smr[w] = lsum;
    __syncthreads();
    if (tid == 0) partial[bid] = smr[0] + smr[1] + smr[2] + smr[3];
}

// stage 1: grid-stride partial sums (gemm positive, link negative) -> 128 values
__global__ __launch_bounds__(256) void reduce1_kernel(
    const float* __restrict__ pg, const float* __restrict__ pl, int nlink,
    float* __restrict__ fpart)
{
    float s = 0.f;
    for (int k = blockIdx.x * 256 + threadIdx.x; k < NB_GEMM; k += NB_FIN * 256) s += pg[k];
    for (int k = blockIdx.x * 256 + threadIdx.x; k < nlink; k += NB_FIN * 256) s -= pl[k];
    #pragma unroll
    for (int m = 32; m >= 1; m >>= 1) s += __shfl_xor(s, m, 64);
    __shared__ float sm[4];
    int w = threadIdx.x >> 6;
    if ((threadIdx.x & 63) == 0) sm[w] = s;
    __syncthreads();
    if (threadIdx.x == 0) fpart[blockIdx.x] = sm[0] + sm[1] + sm[2] + sm[3];
}

// stage 2: 128 -> 1
__global__ __launch_bounds__(128) void reduce2_kernel(
    const float* __restrict__ fpart, float* __restrict__ out)
{
    float s = fpart[threadIdx.x];
    #pragma unroll
    for (int m = 32; m >= 1; m >>= 1) s += __shfl_xor(s, m, 64);
    __shared__ float sm[2];
    if ((threadIdx.x & 63) == 0) sm[threadIdx.x >> 6] = s;
    __syncthreads();
    if (threadIdx.x == 0) out[0] = sm[0] + sm[1];
}

extern "C" void kernel_launch(void* const* d_in, const int* in_sizes, int n_in,
                              void* d_out, int out_size, void* d_ws, size_t ws_size,
                              hipStream_t stream) {
    const int* edges = (const int*)d_in[0];
    const int* nodes_p_star = (const int*)d_in[1];
    const int* nodes_p = (const int*)d_in[2];
    const float* beta_p = (const float*)d_in[3];
    const float* beta_p_star = (const float*)d_in[4];
    const float* p = (const float*)d_in[5];
    const float* p_star = (const float*)d_in[6];

    char* ws = (char*)d_ws;
    float* pgemm = (float*)(ws + OFF_PGEMM);
    float* plink = (float*)(ws + OFF_PLINK);
    float* fpart = (float*)(ws + OFF_FPART);
    _Float16* psh = (_Float16*)(ws + OFF_PSH);   // gathered p_star rows (A / Ns)
    _Float16* pph = (_Float16*)(ws + OFF_PPH);   // gathered p rows (B / Np)
    float* n2s = (float*)(ws + OFF_N2S);
    float* n2p = (float*)(ws + OFF_N2P);
    float* bps = (float*)(ws + OFF_BPS);
    float* bp = (float*)(ws + OFF_BP);

    gather_kernel<<<BATCH / 8, 256, 0, stream>>>(p_star, beta_p_star, nodes_p_star, psh, n2s, bps);
    gather_kernel<<<BATCH / 8, 256, 0, stream>>>(p, beta_p, nodes_p, pph, n2p, bp);

    const bool use16 = ws_size >= (size_t)OFF_END;
    int nlink;
    if (use16) {
        _Float16* p16 = (_Float16*)(ws + OFF_P16);
        _Float16* ps16 = (_Float16*)(ws + OFF_PS16);
        convert_kernel<<<N_NODES / 8, 256, 0, stream>>>(p, p16);
        convert_kernel<<<N_NODES / 8, 256, 0, stream>>>(p_star, ps16);
        link16_kernel<<<NB_LINK16, 256, 0, stream>>>(edges, beta_p, beta_p_star, p16, ps16, plink);
        nlink = NB_LINK16;
    } else {
        link32_kernel<<<NB_LINK32, 256, 0, stream>>>(edges, beta_p, beta_p_star, p, p_star, plink);
        nlink = NB_LINK32;
    }

    nonlink_kernel<<<dim3(129, 64), 256, 0, stream>>>(psh, pph, n2s, n2p, bps, bp, pgemm);

    reduce1_kernel<<<NB_FIN, 256, 0, stream>>>(pgemm, plink, nlink, fpart);
    reduce2_kernel<<<1, 128, 0, stream>>>(fpart, (float*)d_out);
}